// Round 7
// baseline (172.703 us; speedup 1.0000x reference)
//
#include <hip/hip_runtime.h>

// GraphSage on MI355X — round 16.
//   prep  : feat fp32 -> fb bf16 + f8 fp8 e4m3 [N][128B] + w1,w2 -> w1T,w2T bf16 [n][k]
//   k1_agg: (round-14) quarter-buffer pipelined DMA gather, counted vmcnt(4), 8KB LDS.
//   g1    : round-11 skeleton (W one-shot frag-order DMA into 64KB LDS, ONE barrier,
//           barrier-free MFMA loop) + the missing piece: A panel via 16 inline-asm
//           global_load_dwordx4 ("=v" outputs) -> genuinely 16 loads in flight.
//           Round-10/11 showed hipcc serializes compiler-issued VGPR-dest loads
//           (68 VGPR, ~1 in flight); round-14's g2 proved the asm form works.
//           2 blocks/CU (64KB LDS), 8 waves/CU for cross-wave overlap.
//   g2    : (round-14) fused layer-2, inline-asm parallel neighbor loads.

#define N_NODES 100000
#define DEG     16
#define FDIM    128
#define HDIM    128
#define B_NODES 8192

typedef __attribute__((ext_vector_type(8))) short bf16x8;
typedef __attribute__((ext_vector_type(8))) unsigned short u16x8;
typedef __attribute__((ext_vector_type(4))) float f32x4;
typedef __attribute__((ext_vector_type(2))) float f32x2;

static __device__ __forceinline__ unsigned short f2bf(float f) {
    union { float f; unsigned u; } v; v.f = f;
    unsigned r = v.u + 0x7fff + ((v.u >> 16) & 1);   // RNE
    return (unsigned short)(r >> 16);
}
static __device__ __forceinline__ float bf2f(unsigned short b) {
    union { unsigned u; float f; } v; v.u = ((unsigned)b) << 16;
    return v.f;
}

// blocks 0..6249: cast feat -> fb (bf16) + f8 (fp8). blocks 6250..6265: w1/w2 transpose.
__global__ __launch_bounds__(256)
void prep(const float* __restrict__ feat, const float* __restrict__ w1,
          const float* __restrict__ w2, unsigned short* __restrict__ fb,
          unsigned char* __restrict__ f8,
          unsigned short* __restrict__ w1T, unsigned short* __restrict__ w2T) {
    if (blockIdx.x < 6250) {
        long e = ((long)blockIdx.x * 256 + threadIdx.x) * 8;   // 6250*256*8 = 12.8M exact
        float4 v0 = *(const float4*)(feat + e);
        float4 v1 = *(const float4*)(feat + e + 4);
        u16x8 ob;
        ob[0] = f2bf(v0.x); ob[1] = f2bf(v0.y); ob[2] = f2bf(v0.z); ob[3] = f2bf(v0.w);
        ob[4] = f2bf(v1.x); ob[5] = f2bf(v1.y); ob[6] = f2bf(v1.z); ob[7] = f2bf(v1.w);
        *(u16x8*)(fb + e) = ob;
        int p0 = 0, p1 = 0;
        p0 = __builtin_amdgcn_cvt_pk_fp8_f32(v0.x, v0.y, p0, false);
        p0 = __builtin_amdgcn_cvt_pk_fp8_f32(v0.z, v0.w, p0, true);
        p1 = __builtin_amdgcn_cvt_pk_fp8_f32(v1.x, v1.y, p1, false);
        p1 = __builtin_amdgcn_cvt_pk_fp8_f32(v1.z, v1.w, p1, true);
        uint2 o8; o8.x = (unsigned)p0; o8.y = (unsigned)p1;
        *(uint2*)(f8 + e) = o8;
    } else {
        int bid = blockIdx.x - 6250;
        const float* w = (bid < 8) ? w1 : w2;
        unsigned short* wT = (bid < 8) ? w1T : w2T;
        int kb = (bid & 7) * 32;
        int n = threadIdx.x & 127, dk = threadIdx.x >> 7;
#pragma unroll
        for (int i = 0; i < 16; ++i) {
            int k = kb + dk * 16 + i;
            wT[n * 256 + k] = f2bf(w[k * 128 + n]);   // read coalesced over n
        }
    }
}

// Quarter-buffer pipelined gather. 8 nodes/block, 1 wave, no barriers.
__global__ __launch_bounds__(64)
void k1_agg(const unsigned char* __restrict__ f8, const int* __restrict__ nbr,
            unsigned short* __restrict__ agg) {
    __shared__ unsigned char L[8][1024];   // 8 KB -> 20 blocks/CU
    const int lane = threadIdx.x;
    const int node = blockIdx.x * 8 + (lane >> 3);   // 12500*8 = 100000 exact
    const int sub = lane & 7;
    const int* idx = nbr + node * DEG;
    int4 i0 = *(const int4*)(idx);
    int4 i1 = *(const int4*)(idx + 4);
    int4 i2 = *(const int4*)(idx + 8);
    int4 i3 = *(const int4*)(idx + 12);
    const int id[16] = {i0.x, i0.y, i0.z, i0.w, i1.x, i1.y, i1.z, i1.w,
                        i2.x, i2.y, i2.z, i2.w, i3.x, i3.y, i3.z, i3.w};

#define K1_ISSUE(Q, B)                                                          \
    _Pragma("unroll")                                                           \
    for (int j_ = 0; j_ < 4; ++j_) {                                            \
        const unsigned char* src_ = f8 + (long)id[(Q) * 4 + j_] * 128 + sub * 16; \
        __builtin_amdgcn_global_load_lds(                                       \
            (const __attribute__((address_space(1))) unsigned int*)src_,        \
            (__attribute__((address_space(3))) unsigned int*)                   \
                (&L[(B) * 4 + j_][lane * 16]), 16, 0, 0);                       \
    }

    f32x2 s2[8];
#pragma unroll
    for (int j = 0; j < 8; ++j) s2[j] = (f32x2){0.f, 0.f};

#define K1_CONV(B)                                                              \
    _Pragma("unroll")                                                           \
    for (int j_ = 0; j_ < 4; ++j_) {                                            \
        uint4 v = *(const uint4*)(&L[(B) * 4 + j_][lane * 16]);                 \
        s2[0] += __builtin_amdgcn_cvt_pk_f32_fp8((int)v.x, false);              \
        s2[1] += __builtin_amdgcn_cvt_pk_f32_fp8((int)v.x, true);               \
        s2[2] += __builtin_amdgcn_cvt_pk_f32_fp8((int)v.y, false);              \
        s2[3] += __builtin_amdgcn_cvt_pk_f32_fp8((int)v.y, true);               \
        s2[4] += __builtin_amdgcn_cvt_pk_f32_fp8((int)v.z, false);              \
        s2[5] += __builtin_amdgcn_cvt_pk_f32_fp8((int)v.z, true);               \
        s2[6] += __builtin_amdgcn_cvt_pk_f32_fp8((int)v.w, false);              \
        s2[7] += __builtin_amdgcn_cvt_pk_f32_fp8((int)v.w, true);               \
    }

    K1_ISSUE(0, 0);
    K1_ISSUE(1, 1);
    asm volatile("s_waitcnt vmcnt(4)" ::: "memory");
    __builtin_amdgcn_sched_barrier(0);
    K1_CONV(0);
    __builtin_amdgcn_sched_barrier(0);
    K1_ISSUE(2, 0);
    asm volatile("s_waitcnt vmcnt(4)" ::: "memory");
    __builtin_amdgcn_sched_barrier(0);
    K1_CONV(1);
    __builtin_amdgcn_sched_barrier(0);
    K1_ISSUE(3, 1);
    asm volatile("s_waitcnt vmcnt(4)" ::: "memory");
    __builtin_amdgcn_sched_barrier(0);
    K1_CONV(0);
    asm volatile("s_waitcnt vmcnt(0)" ::: "memory");
    __builtin_amdgcn_sched_barrier(0);
    K1_CONV(1);

    u16x8 o0, o1;
#pragma unroll
    for (int j = 0; j < 8; ++j) {
        o0[j] = f2bf(s2[j >> 1][j & 1] * 0.0625f);
        o1[j] = f2bf(s2[4 + (j >> 1)][j & 1] * 0.0625f);
    }
    unsigned short* dst = agg + (long)node * 128 + sub * 16;
    *(u16x8*)dst = o0;
    *(u16x8*)(dst + 8) = o1;
}

// GEMM: h1[N,128] = [fb | agg] @ w1T. 128 rows/block, 32 rows/wave.
//   - W: one-shot DMA into 64KB LDS in MFMA-fragment order (source-permuted;
//     correctness-verified in round 11). K-loop W reads = lane-linear ds_read_b128.
//   - A: 16 inline-asm global_load_dwordx4 per lane, ALL in flight (the round-11
//     version used compiler loads, which hipcc serializes).
//   - ONE vmcnt(0)+__syncthreads; then 128 MFMAs with zero barriers/vmem.
__global__ __launch_bounds__(256, 2)
void g1(const unsigned short* __restrict__ fb, const unsigned short* __restrict__ agg,
        const unsigned short* __restrict__ w1T, unsigned short* __restrict__ h1) {
    __shared__ unsigned short Wlds[64 * 512];   // 64 KB -> 2 blocks/CU
    const int t = threadIdx.x, wave = t >> 6, lane = t & 63;
    const int m16 = lane & 15, quad = lane >> 4;
    const long row0 = (long)blockIdx.x * 128 + wave * 32;

    // A panel: 16 forced-parallel 16B loads (rows beyond N read adjacent ws regions,
    // in-bounds garbage, masked on store).
    uint4 a0_0, a0_1, a1_0, a1_1, a2_0, a2_1, a3_0, a3_1;
    uint4 a4_0, a4_1, a5_0, a5_1, a6_0, a6_1, a7_0, a7_1;
#define G1_LOAD(KC, MT, V)                                                       \
    {                                                                            \
        const unsigned short* As_ =                                              \
            ((KC) < 4) ? (fb + (KC) * 32) : (agg + ((KC) - 4) * 32);             \
        unsigned long long ad_ =                                                 \
            (unsigned long long)(As_ + (row0 + (MT) * 16 + m16) * 128 + quad * 8); \
        asm volatile("global_load_dwordx4 %0, %1, off"                           \
                     : "=v"(V) : "v"(ad_) : "memory");                           \
    }
    G1_LOAD(0, 0, a0_0) G1_LOAD(0, 1, a0_1)
    G1_LOAD(1, 0, a1_0) G1_LOAD(1, 1, a1_1)
    G1_LOAD(2, 0, a2_0) G1_LOAD(2, 1, a2_1)
    G1_LOAD(3, 0, a3_0) G1_LOAD(3, 1, a3_1)
    G1_LOAD(4, 0, a4_0) G1_LOAD(4, 1, a4_1)
    G1_LOAD(5, 0, a5_0) G1_LOAD(5, 1, a5_1)
    G1_LOAD(6, 0, a6_0) G1_LOAD(6, 1, a6_1)
    G1_LOAD(7, 0, a7_0) G1_LOAD(7, 1, a7_1)
#undef G1_LOAD

    // W -> LDS in fragment order. LDS dest linear (base + o16*16B); fragment
    // permutation applied to the GLOBAL source address (round-11 verified).
#pragma unroll
    for (int i = 0; i < 16; ++i) {
        int o16 = i * 256 + t;            // 16B-chunk index 0..4095
        int chunk = o16 >> 6;             // = kc*8 + nt (wave-uniform)
        int kc = chunk >> 3, nt = chunk & 7;
        int n = nt * 16 + m16;
        int k0 = kc * 32 + quad * 8;
        const unsigned short* src = w1T + n * 256 + k0;
        __builtin_amdgcn_global_load_lds(
            (const __attribute__((address_space(1))) unsigned int*)src,
            (__attribute__((address_space(3))) unsigned int*)
                (((char*)Wlds) + (long)o16 * 16),
            16, 0, 0);
    }

    asm volatile("s_waitcnt vmcnt(0)" ::: "memory");   // A regs + this wave's W DMA
    __builtin_amdgcn_sched_barrier(0);
    __syncthreads();                                   // all waves' W DMA visible

    f32x4 acc[2][8] = {};
#define G1_KC(KC, V0, V1)                                                        \
    {                                                                            \
        bf16x8 a0 = __builtin_bit_cast(bf16x8, V0);                              \
        bf16x8 a1 = __builtin_bit_cast(bf16x8, V1);                              \
        _Pragma("unroll")                                                        \
        for (int nt = 0; nt < 8; ++nt) {                                         \
            bf16x8 bv = *(const bf16x8*)(Wlds + ((KC) * 8 + nt) * 512 + lane * 8); \
            acc[0][nt] = __builtin_amdgcn_mfma_f32_16x16x32_bf16(a0, bv, acc[0][nt], 0, 0, 0); \
            acc[1][nt] = __builtin_amdgcn_mfma_f32_16x16x32_bf16(a1, bv, acc[1][nt], 0, 0, 0); \
        }                                                                        \
    }
    G1_KC(0, a0_0, a0_1)
    G1_KC(1, a1_0, a1_1)
    G1_KC(2, a2_0, a2_1)
    G1_KC(3, a3_0, a3_1)
    G1_KC(4, a4_0, a4_1)
    G1_KC(5, a5_0, a5_1)
    G1_KC(6, a6_0, a6_1)
    G1_KC(7, a7_0, a7_1)
#undef G1_KC

    // C layout: row = quad*4 + reg, col = nt*16 + m16
#pragma unroll
    for (int mt = 0; mt < 2; ++mt)
#pragma unroll
        for (int reg = 0; reg < 4; ++reg) {
            long grow = row0 + mt * 16 + quad * 4 + reg;
            if (grow >= N_NODES) continue;
#pragma unroll
            for (int nt = 0; nt < 8; ++nt)
                h1[grow * HDIM + nt * 16 + m16] = f2bf(acc[mt][nt][reg]);
        }
}

// Layer 2 fused: 64 batch rows per 256-thread block. 128 blocks exact.
__global__ __launch_bounds__(256)
void g2_fused(const unsigned short* __restrict__ h1, const unsigned short* __restrict__ w2T,
              const int* __restrict__ nbr, const int* __restrict__ nodes,
              float* __restrict__ out) {
    __shared__ unsigned short X2[64][264];
    const int t = threadIdx.x, wave = t >> 6, lane = t & 63;
    const int m16 = lane & 15, quad = lane >> 4;
    const int b0 = blockIdx.x * 64;
    const int colb = m16 * 8;

    for (int g = 0; g < 4; ++g) {
        int Ln = wave * 16 + g * 4 + quad;
        int node = nodes[b0 + Ln];
        *(u16x8*)(&X2[Ln][colb]) = *(const u16x8*)(h1 + (long)node * HDIM + colb);
        const int* idx = nbr + node * DEG;
        int4 i0 = *(const int4*)(idx);
        int4 i1 = *(const int4*)(idx + 4);
        int4 i2 = *(const int4*)(idx + 8);
        int4 i3 = *(const int4*)(idx + 12);
        const int id[16] = {i0.x, i0.y, i0.z, i0.w, i1.x, i1.y, i1.z, i1.w,
                            i2.x, i2.y, i2.z, i2.w, i3.x, i3.y, i3.z, i3.w};

        uint4 v0, v1, v2, v3, v4, v5, v6, v7, v8, v9, v10, v11, v12, v13, v14, v15;
#define G2_LOAD(K)                                                               \
        {                                                                        \
            unsigned long long a_ =                                              \
                (unsigned long long)(h1 + (long)id[K] * HDIM + colb);            \
            asm volatile("global_load_dwordx4 %0, %1, off"                       \
                         : "=v"(v##K) : "v"(a_) : "memory");                     \
        }
        G2_LOAD(0)  G2_LOAD(1)  G2_LOAD(2)  G2_LOAD(3)
        G2_LOAD(4)  G2_LOAD(5)  G2_LOAD(6)  G2_LOAD(7)
        G2_LOAD(8)  G2_LOAD(9)  G2_LOAD(10) G2_LOAD(11)
        G2_LOAD(12) G2_LOAD(13) G2_LOAD(14) G2_LOAD(15)
#undef G2_LOAD

        float s[8] = {0.f, 0.f, 0.f, 0.f, 0.f, 0.f, 0.f, 0.f};
        asm volatile("s_waitcnt vmcnt(8)" ::: "memory");
        __builtin_amdgcn_sched_barrier(0);
#define G2_SUM(K)                                                                \
        {                                                                        \
            u16x8 w_ = __builtin_bit_cast(u16x8, v##K);                          \
            _Pragma("unroll")                                                    \
            for (int j = 0; j < 8; ++j) s[j] += bf2f(w_[j]);                     \
        }
        G2_SUM(0) G2_SUM(1) G2_SUM(2) G2_SUM(3)
        G2_SUM(4) G2_SUM(5) G2_SUM(6) G2_SUM(7)
        asm volatile("s_waitcnt vmcnt(0)" ::: "memory");
        __builtin_amdgcn_sched_barrier(0);
        G2_SUM(8)  G2_SUM(9)  G2_SUM(10) G2_SUM(11)
        G2_SUM(12) G2_SUM(13) G2_SUM(14) G2_SUM(15)
#undef G2_SUM

        u16x8 o;
#pragma unroll
        for (int j = 0; j < 8; ++j) o[j] = f2bf(s[j] * 0.0625f);
        *(u16x8*)(&X2[Ln][128 + colb]) = o;
    }
    __syncthreads();

    f32x4 acc[8] = {};
#pragma unroll
    for (int kc = 0; kc < 8; ++kc) {
        bf16x8 a = *(const bf16x8*)(&X2[wave * 16 + m16][kc * 32 + quad * 8]);
#pragma unroll
        for (int nt = 0; nt < 8; ++nt) {
            bf16x8 b = *(const bf16x8*)(w2T + (nt * 16 + m16) * 256 + kc * 32 + quad * 8);
            acc[nt] = __builtin_amdgcn_mfma_f32_16x16x32_bf16(a, b, acc[nt], 0, 0, 0);
        }
    }

#pragma unroll
    for (int nt = 0; nt < 8; ++nt)
#pragma unroll
        for (int reg = 0; reg < 4; ++reg) {
            int row = b0 + wave * 16 + quad * 4 + reg;
            out[(long)row * 128 + nt * 16 + m16] = acc[nt][reg];
        }
}

extern "C" void kernel_launch(void* const* d_in, const int* in_sizes, int n_in,
                              void* d_out, int out_size, void* d_ws, size_t ws_size,
                              hipStream_t stream) {
    const float* feat  = (const float*)d_in[0];
    const float* w1    = (const float*)d_in[1];
    const float* w2    = (const float*)d_in[2];
    const int*   nbr   = (const int*)d_in[3];
    const int*   nodes = (const int*)d_in[4];
    float* out = (float*)d_out;

    char* ws = (char*)d_ws;
    unsigned short* fb  = (unsigned short*)ws;                       // N*128 bf16 = 25.6 MB
    unsigned char*  f8  = (unsigned char*)(ws + 25600000);           // N*128 fp8  = 12.8 MB
    unsigned short* agg = (unsigned short*)(ws + 38400000);          // N*128 bf16 = 25.6 MB
    unsigned short* h1  = (unsigned short*)(ws + 64000000);          // N*128 bf16 = 25.6 MB
    unsigned short* w1T = (unsigned short*)(ws + 89600000);          // 64 KB
    unsigned short* w2T = (unsigned short*)(ws + 89665536);          // 64 KB

    prep<<<6266, 256, 0, stream>>>(feat, w1, w2, fb, f8, w1T, w2T);
    k1_agg<<<12500, 64, 0, stream>>>(f8, nbr, agg);
    g1<<<(N_NODES + 127) / 128, 256, 0, stream>>>(fb, agg, w1T, h1);
    g2_fused<<<B_NODES / 64, 256, 0, stream>>>(h1, w2T, nbr, nodes, out);
}

// Round 8
// 164.543 us; speedup vs baseline: 1.0496x; 1.0496x over previous
//
#include <hip/hip_runtime.h>

// GraphSage on MI355X — round 17: RESTORE of the measured-best configuration
// (round-9 anchor; 165.2 µs prior session, 164.6 µs round 0 this session).
// Session post-mortem (rounds 10-16, all regressed or tied):
//   - no-LDS g1 (compiler VGPR-dest loads): +27 µs — hipcc serializes them (~1 in flight).
//   - frag-order LDS + counted vmcnt:       +5 µs — round-9 frag reads were already
//     conflict-free (64 lanes span a contiguous 1KB line); extra barrier cost.
//   - one-shot 128KB staging:               +7 µs — 1 block/CU kills TLP.
//   - one-shot W + 16 asm A-loads:          +7 µs — same; 2 blocks/CU insufficient.
//   - k1 quarter-buffer, g2 asm loads:      neutral (within noise).
// Budget closes: prep ~14 + k1 ~20 + g1 ~38 + g2 ~8 ≈ 80 µs kernels + ~82 µs harness
// fill in the timed window ≈ the anchor. The 4-blocks/CU ping-pong g1 is the local
// optimum: 782 blocks all co-resident, staging latency hidden by cross-block TLP.
//   prep  : feat fp32 -> fb bf16 (GEMM self operand) + f8 fp8 e4m3 [N][128B] (gather src)
//           + w1,w2 -> w1T,w2T bf16 [n][k]
//   k1_agg: async-DMA gather, 1-wave blocks (no barriers): 16 global_load_lds per lane,
//           raw wave-local s_waitcnt vmcnt(0), packed f32x2 adds. 16KB LDS -> 10 blk/CU.
//   g1    : h1 = [fb | agg] @ w1T.  m97-style BK=32 double-buffered global_load_lds,
//           4 blocks/CU (staging-latency-bound; MFMA is ~6% of cycles).
//   g2    : out = [h1[node] | mean h1[nbr]] @ w2T  (fused, 64 rows/block)

#define N_NODES 100000
#define DEG     16
#define FDIM    128
#define HDIM    128
#define B_NODES 8192

typedef __attribute__((ext_vector_type(8))) short bf16x8;
typedef __attribute__((ext_vector_type(8))) unsigned short u16x8;
typedef __attribute__((ext_vector_type(4))) float f32x4;
typedef __attribute__((ext_vector_type(2))) float f32x2;

static __device__ __forceinline__ unsigned short f2bf(float f) {
    union { float f; unsigned u; } v; v.f = f;
    unsigned r = v.u + 0x7fff + ((v.u >> 16) & 1);   // RNE
    return (unsigned short)(r >> 16);
}
static __device__ __forceinline__ float bf2f(unsigned short b) {
    union { unsigned u; float f; } v; v.u = ((unsigned)b) << 16;
    return v.f;
}

// blocks 0..6249: cast feat -> fb (bf16) + f8 (fp8). blocks 6250..6265: w1/w2 transpose.
__global__ __launch_bounds__(256)
void prep(const float* __restrict__ feat, const float* __restrict__ w1,
          const float* __restrict__ w2, unsigned short* __restrict__ fb,
          unsigned char* __restrict__ f8,
          unsigned short* __restrict__ w1T, unsigned short* __restrict__ w2T) {
    if (blockIdx.x < 6250) {
        long e = ((long)blockIdx.x * 256 + threadIdx.x) * 8;   // 6250*256*8 = 12.8M exact
        float4 v0 = *(const float4*)(feat + e);
        float4 v1 = *(const float4*)(feat + e + 4);
        u16x8 ob;
        ob[0] = f2bf(v0.x); ob[1] = f2bf(v0.y); ob[2] = f2bf(v0.z); ob[3] = f2bf(v0.w);
        ob[4] = f2bf(v1.x); ob[5] = f2bf(v1.y); ob[6] = f2bf(v1.z); ob[7] = f2bf(v1.w);
        *(u16x8*)(fb + e) = ob;
        int p0 = 0, p1 = 0;
        p0 = __builtin_amdgcn_cvt_pk_fp8_f32(v0.x, v0.y, p0, false);
        p0 = __builtin_amdgcn_cvt_pk_fp8_f32(v0.z, v0.w, p0, true);
        p1 = __builtin_amdgcn_cvt_pk_fp8_f32(v1.x, v1.y, p1, false);
        p1 = __builtin_amdgcn_cvt_pk_fp8_f32(v1.z, v1.w, p1, true);
        uint2 o8; o8.x = (unsigned)p0; o8.y = (unsigned)p1;
        *(uint2*)(f8 + e) = o8;
    } else {
        int bid = blockIdx.x - 6250;
        const float* w = (bid < 8) ? w1 : w2;
        unsigned short* wT = (bid < 8) ? w1T : w2T;
        int kb = (bid & 7) * 32;
        int n = threadIdx.x & 127, dk = threadIdx.x >> 7;
#pragma unroll
        for (int i = 0; i < 16; ++i) {
            int k = kb + dk * 16 + i;
            wT[n * 256 + k] = f2bf(w[k * 128 + n]);   // read coalesced over n
        }
    }
}

// Async-DMA gather, 1-wave blocks. 8 nodes/block (8 lanes x 16 B = full 128-B row).
// No __syncthreads anywhere: the only wait is this wave's own vmcnt(0).
__global__ __launch_bounds__(64)
void k1_agg(const unsigned char* __restrict__ f8, const int* __restrict__ nbr,
            unsigned short* __restrict__ agg) {
    __shared__ unsigned char L[16][1024];   // 16 KB: [d][lane*16B] -> 10 blocks/CU
    const int lane = threadIdx.x;
    const int node = blockIdx.x * 8 + (lane >> 3);   // 12500*8 = 100000 exact
    const int sub = lane & 7;
    const int* idx = nbr + node * DEG;
    int4 i0 = *(const int4*)(idx);
    int4 i1 = *(const int4*)(idx + 4);
    int4 i2 = *(const int4*)(idx + 8);
    int4 i3 = *(const int4*)(idx + 12);
    const int id[16] = {i0.x, i0.y, i0.z, i0.w, i1.x, i1.y, i1.z, i1.w,
                        i2.x, i2.y, i2.z, i2.w, i3.x, i3.y, i3.z, i3.w};
#pragma unroll
    for (int d = 0; d < DEG; ++d) {
        const unsigned char* src = f8 + (long)id[d] * 128 + sub * 16;
        __builtin_amdgcn_global_load_lds(
            (const __attribute__((address_space(1))) unsigned int*)src,
            (__attribute__((address_space(3))) unsigned int*)(&L[d][lane * 16]),
            16, 0, 0);
    }
    asm volatile("s_waitcnt vmcnt(0)" ::: "memory");   // wave-local DMA drain

    f32x2 s2[8];
#pragma unroll
    for (int j = 0; j < 8; ++j) s2[j] = (f32x2){0.f, 0.f};
#pragma unroll
    for (int d = 0; d < DEG; ++d) {
        uint4 v = *(const uint4*)(&L[d][lane * 16]);
        s2[0] += __builtin_amdgcn_cvt_pk_f32_fp8((int)v.x, false);
        s2[1] += __builtin_amdgcn_cvt_pk_f32_fp8((int)v.x, true);
        s2[2] += __builtin_amdgcn_cvt_pk_f32_fp8((int)v.y, false);
        s2[3] += __builtin_amdgcn_cvt_pk_f32_fp8((int)v.y, true);
        s2[4] += __builtin_amdgcn_cvt_pk_f32_fp8((int)v.z, false);
        s2[5] += __builtin_amdgcn_cvt_pk_f32_fp8((int)v.z, true);
        s2[6] += __builtin_amdgcn_cvt_pk_f32_fp8((int)v.w, false);
        s2[7] += __builtin_amdgcn_cvt_pk_f32_fp8((int)v.w, true);
    }
    u16x8 o0, o1;
#pragma unroll
    for (int j = 0; j < 8; ++j) {
        o0[j] = f2bf(s2[j >> 1][j & 1] * 0.0625f);
        o1[j] = f2bf(s2[4 + (j >> 1)][j & 1] * 0.0625f);
    }
    unsigned short* dst = agg + (long)node * 128 + sub * 16;
    *(u16x8*)dst = o0;
    *(u16x8*)(dst + 8) = o1;
}

// Stage one K-chunk (A rows + W rows, 8 KB each) into LDS buf via global_load_lds.
#define STAGE(KC, BUF)                                                                        \
    do {                                                                                      \
        const unsigned short* s0_ = ((KC) < 4) ? (fb + (KC) * 32) : (agg + ((KC) - 4) * 32);  \
        _Pragma("unroll")                                                                     \
        for (int j_ = 0; j_ < 2; ++j_) {                                                      \
            long grow_ = row0 + (t >> 2) + j_ * 64;                                           \
            const unsigned short* ga_ = s0_ + grow_ * 128 + (t & 3) * 8;                      \
            __builtin_amdgcn_global_load_lds(                                                 \
                (const __attribute__((address_space(1))) unsigned int*)ga_,                   \
                (__attribute__((address_space(3))) unsigned int*)                             \
                    (&AsS[(BUF) * 4096 + wave * 512 + j_ * 2048 + lane * 8]), 16, 0, 0);      \
            const unsigned short* gw_ = w1T + ((t >> 2) + j_ * 64) * 256 + (KC) * 32 + (t & 3) * 8; \
            __builtin_amdgcn_global_load_lds(                                                 \
                (const __attribute__((address_space(1))) unsigned int*)gw_,                   \
                (__attribute__((address_space(3))) unsigned int*)                             \
                    (&WsS[(BUF) * 4096 + wave * 512 + j_ * 2048 + lane * 8]), 16, 0, 0);      \
        }                                                                                     \
    } while (0)

// GEMM: h1[N,128] = [fb | agg] @ w1T. 128 rows/block, BK=32, double-buffered async LDS.
// 4 blocks/CU: staging-latency-bound, so TLP is the lever (MFMA ~6% of cycles).
__global__ __launch_bounds__(256, 4)
void g1(const unsigned short* __restrict__ fb, const unsigned short* __restrict__ agg,
        const unsigned short* __restrict__ w1T, unsigned short* __restrict__ h1) {
    __shared__ unsigned short AsS[2 * 4096];   // 2 x 128 rows x 32 k (8 KB each)
    __shared__ unsigned short WsS[2 * 4096];
    const int t = threadIdx.x, wave = t >> 6, lane = t & 63;
    const int m16 = lane & 15, quad = lane >> 4;
    const long row0 = (long)blockIdx.x * 128;

    f32x4 acc[2][8] = {};
    STAGE(0, 0);
#pragma unroll
    for (int kc = 0; kc < 8; ++kc) {
        __syncthreads();                       // drains vmcnt -> staging of kc complete
        if (kc < 7) {
            switch (kc + 1) {
                case 1: STAGE(1, 1); break;
                case 2: STAGE(2, 0); break;
                case 3: STAGE(3, 1); break;
                case 4: STAGE(4, 0); break;
                case 5: STAGE(5, 1); break;
                case 6: STAGE(6, 0); break;
                case 7: STAGE(7, 1); break;
            }
        }
        const unsigned short* Ab = &AsS[(kc & 1) * 4096];
        const unsigned short* Wb = &WsS[(kc & 1) * 4096];
        bf16x8 a0 = *(const bf16x8*)(Ab + (wave * 32 + m16) * 32 + quad * 8);
        bf16x8 a1 = *(const bf16x8*)(Ab + (wave * 32 + 16 + m16) * 32 + quad * 8);
#pragma unroll
        for (int nt = 0; nt < 8; ++nt) {
            bf16x8 bv = *(const bf16x8*)(Wb + (nt * 16 + m16) * 32 + quad * 8);
            acc[0][nt] = __builtin_amdgcn_mfma_f32_16x16x32_bf16(a0, bv, acc[0][nt], 0, 0, 0);
            acc[1][nt] = __builtin_amdgcn_mfma_f32_16x16x32_bf16(a1, bv, acc[1][nt], 0, 0, 0);
        }
    }

    // C layout: row = quad*4 + reg, col = nt*16 + m16
#pragma unroll
    for (int mt = 0; mt < 2; ++mt)
#pragma unroll
        for (int reg = 0; reg < 4; ++reg) {
            long grow = row0 + wave * 32 + mt * 16 + quad * 4 + reg;
            if (grow >= N_NODES) continue;
#pragma unroll
            for (int nt = 0; nt < 8; ++nt)
                h1[grow * HDIM + nt * 16 + m16] = f2bf(acc[mt][nt][reg]);
        }
}

// Layer 2 fused: 64 batch rows per 256-thread block. 128 blocks exact.
__global__ __launch_bounds__(256)
void g2_fused(const unsigned short* __restrict__ h1, const unsigned short* __restrict__ w2T,
              const int* __restrict__ nbr, const int* __restrict__ nodes,
              float* __restrict__ out) {
    __shared__ unsigned short X2[64][264];
    const int t = threadIdx.x, wave = t >> 6, lane = t & 63;
    const int m16 = lane & 15, quad = lane >> 4;
    const int b0 = blockIdx.x * 64;
    const int colb = m16 * 8;

    for (int g = 0; g < 4; ++g) {
        int Ln = wave * 16 + g * 4 + quad;
        int node = nodes[b0 + Ln];
        *(u16x8*)(&X2[Ln][colb]) = *(const u16x8*)(h1 + node * HDIM + colb);
        const int* idx = nbr + node * DEG;
        float s[8] = {0.f, 0.f, 0.f, 0.f, 0.f, 0.f, 0.f, 0.f};
#pragma unroll
        for (int d = 0; d < DEG; ++d) {
            int nb = idx[d];
            u16x8 v = *(const u16x8*)(h1 + nb * HDIM + colb);
#pragma unroll
            for (int j = 0; j < 8; ++j) s[j] += bf2f(v[j]);
        }
        u16x8 o;
#pragma unroll
        for (int j = 0; j < 8; ++j) o[j] = f2bf(s[j] * 0.0625f);
        *(u16x8*)(&X2[Ln][128 + colb]) = o;
    }
    __syncthreads();

    f32x4 acc[8] = {};
#pragma unroll
    for (int kc = 0; kc < 8; ++kc) {
        bf16x8 a = *(const bf16x8*)(&X2[wave * 16 + m16][kc * 32 + quad * 8]);
#pragma unroll
        for (int nt = 0; nt < 8; ++nt) {
            bf16x8 b = *(const bf16x8*)(w2T + (nt * 16 + m16) * 256 + kc * 32 + quad * 8);
            acc[nt] = __builtin_amdgcn_mfma_f32_16x16x32_bf16(a, b, acc[nt], 0, 0, 0);
        }
    }

#pragma unroll
    for (int nt = 0; nt < 8; ++nt)
#pragma unroll
        for (int reg = 0; reg < 4; ++reg) {
            int row = b0 + wave * 16 + quad * 4 + reg;
            out[row * 128 + nt * 16 + m16] = acc[nt][reg];
        }
}

extern "C" void kernel_launch(void* const* d_in, const int* in_sizes, int n_in,
                              void* d_out, int out_size, void* d_ws, size_t ws_size,
                              hipStream_t stream) {
    const float* feat  = (const float*)d_in[0];
    const float* w1    = (const float*)d_in[1];
    const float* w2    = (const float*)d_in[2];
    const int*   nbr   = (const int*)d_in[3];
    const int*   nodes = (const int*)d_in[4];
    float* out = (float*)d_out;

    char* ws = (char*)d_ws;
    unsigned short* fb  = (unsigned short*)ws;                       // N*128 bf16 = 25.6 MB
    unsigned char*  f8  = (unsigned char*)(ws + 25600000);           // N*128 fp8  = 12.8 MB
    unsigned short* agg = (unsigned short*)(ws + 38400000);          // N*128 bf16 = 25.6 MB
    unsigned short* h1  = (unsigned short*)(ws + 64000000);          // N*128 bf16 = 25.6 MB
    unsigned short* w1T = (unsigned short*)(ws + 89600000);          // 64 KB
    unsigned short* w2T = (unsigned short*)(ws + 89665536);          // 64 KB

    prep<<<6266, 256, 0, stream>>>(feat, w1, w2, fb, f8, w1T, w2T);
    k1_agg<<<12500, 64, 0, stream>>>(f8, nbr, agg);
    g1<<<(N_NODES + 127) / 128, 256, 0, stream>>>(fb, agg, w1T, h1);
    g2_fused<<<B_NODES / 64, 256, 0, stream>>>(h1, w2T, nbr, nodes, out);
}